// Round 2
// baseline (23826.337 us; speedup 1.0000x reference)
//
#include <hip/hip_runtime.h>
#include <hip/hip_bf16.h>
#include <math.h>

#define NB    32
#define D     768
#define NPP   256
#define NTOK  (NB*NPP)   // 8192
#define NHEAD 12
#define NLAY  12
#define ADA6  4608

__device__ __forceinline__ float silu_f(float x){ return x / (1.f + __expf(-x)); }
__device__ __forceinline__ float gelu_f(float x){ return 0.5f*x*(1.f + erff(x*0.7071067811865476f)); }

// ---------------- patchify + pos-embed ----------------
__global__ void k_patchify(const float* __restrict__ x, const float* __restrict__ cw,
                           const float* __restrict__ cb, float* __restrict__ tok){
  int idx = blockIdx.x*256 + threadIdx.x;        // over NTOK*D
  int d = idx % D, tk = idx / D;
  int b = tk >> 8, n = tk & 255;
  int hi = n >> 4, wi = n & 15;
  float acc = cb[d];
  const float* xb = x + (size_t)b*4*32*32;
  #pragma unroll
  for (int c=0;c<4;c++)
    #pragma unroll
    for (int p1=0;p1<2;p1++)
      #pragma unroll
      for (int p2=0;p2<2;p2++){
        float xv = xb[(c*32 + hi*2+p1)*32 + wi*2+p2];
        acc = fmaf(xv, cw[d*16 + c*4 + p1*2 + p2], acc);
      }
  int i2 = d >> 1;
  float ang = (float)n * powf(10000.f, -(float)(2*i2)/768.f);
  acc += (d & 1) ? cosf(ang) : sinf(ang);
  tok[idx] = acc;
}

// ---------------- time embedding ----------------
__global__ void k_timeembed(const float* __restrict__ t, float* __restrict__ c0){
  int idx = blockIdx.x*256 + threadIdx.x;        // 32*768
  if (idx >= NB*D) return;
  int b = idx / D, d = idx % D;
  int j = (d < 384) ? d : d - 384;
  float emb = expf((float)j * (-logf(10000.f)/383.f));
  float e = t[b]*emb;
  c0[idx] = (d < 384) ? sinf(e) : cosf(e);
}

__global__ void k_silu(const float* __restrict__ in, float* __restrict__ out, int n){
  int i = blockIdx.x*256 + threadIdx.x;
  if (i < n) out[i] = silu_f(in[i]);
}

// ---------------- small GEMM (M<=32): thread per output ----------------
// EPI: 0 plain, 1 silu, 2 +cls_emb[label[m]]
template<int EPI>
__global__ void k_gemm_small(const float* __restrict__ A, const float* __restrict__ W,
                             const float* __restrict__ bias, float* __restrict__ Cout,
                             int N, int K,
                             const float* __restrict__ cls, const int* __restrict__ label){
  int n = blockIdx.x*256 + threadIdx.x;
  int m = blockIdx.y;
  if (n >= N) return;
  const float* a = A + (size_t)m*K;
  float acc = bias[n];
  #pragma unroll 4
  for (int k=0;k<K;k++) acc = fmaf(a[k], W[(size_t)k*N + n], acc);
  if (EPI==1) acc = silu_f(acc);
  if (EPI==2) acc += cls[(size_t)label[m]*D + n];
  Cout[(size_t)m*N + n] = acc;
}

// ---------------- fused LayerNorm + adaLN modulate ----------------
__global__ void k_lnmod(const float* __restrict__ tok, const float* __restrict__ ada,
                        float* __restrict__ outb, int ada_stride, int sh_off, int sc_off){
  int tk = blockIdx.x, tid = threadIdx.x;
  int b = tk >> 8;
  const float* row = tok + (size_t)tk*D;
  float x0 = row[tid], x1 = row[tid+256], x2 = row[tid+512];
  float s1 = x0+x1+x2;
  float s2 = x0*x0 + x1*x1 + x2*x2;
  #pragma unroll
  for (int off=32; off; off>>=1){
    s1 += __shfl_xor(s1, off);
    s2 += __shfl_xor(s2, off);
  }
  __shared__ float r1[4], r2[4];
  int wid = tid >> 6, lane = tid & 63;
  if (lane==0){ r1[wid]=s1; r2[wid]=s2; }
  __syncthreads();
  float t1 = r1[0]+r1[1]+r1[2]+r1[3];
  float t2 = r2[0]+r2[1]+r2[2]+r2[3];
  float mean = t1*(1.f/768.f);
  float var  = t2*(1.f/768.f) - mean*mean;
  float rstd = rsqrtf(var + 1e-6f);
  const float* sh = ada + (size_t)b*ada_stride + sh_off;
  const float* sc = ada + (size_t)b*ada_stride + sc_off;
  float* orow = outb + (size_t)tk*D;
  orow[tid    ] = (x0-mean)*rstd*(1.f+sc[tid    ]) + sh[tid    ];
  orow[tid+256] = (x1-mean)*rstd*(1.f+sc[tid+256]) + sh[tid+256];
  orow[tid+512] = (x2-mean)*rstd*(1.f+sc[tid+512]) + sh[tid+512];
}

// ---------------- tiled fp32 GEMM: 128x128x16, 256 thr, 8x8 micro ----------------
// C[M,N] = epi(A[M,K] @ W[K,N] + bias). EPI: 0 plain, 1 gelu, 2 tok += g*val
template<int EPI>
__launch_bounds__(256)
__global__ void k_gemm_tiled(const float* __restrict__ A, const float* __restrict__ W,
                             const float* __restrict__ bias, float* __restrict__ Cout,
                             int N, int K,
                             const float* __restrict__ adap, int gate_off){
  __shared__ float As[16][132];
  __shared__ float Bs[16][132];
  int tid = threadIdx.x;
  int col0 = blockIdx.x*128, row0 = blockIdx.y*128;
  int tx = tid & 15, ty = tid >> 4;
  float acc[8][8];
  #pragma unroll
  for (int i=0;i<8;i++)
    #pragma unroll
    for (int j=0;j<8;j++) acc[i][j]=0.f;

  for (int kt=0; kt<K; kt+=16){
    #pragma unroll
    for (int p=0;p<8;p++){
      int r = (tid>>4) + p*16;
      int c = tid & 15;
      As[c][r] = A[(size_t)(row0+r)*K + kt + c];
    }
    #pragma unroll
    for (int p=0;p<8;p++){
      int br = (tid>>7) + p*2;
      int bc = tid & 127;
      Bs[br][bc] = W[(size_t)(kt+br)*N + col0 + bc];
    }
    __syncthreads();
    #pragma unroll
    for (int kk=0;kk<16;kk++){
      float a[8], b[8];
      *(float4*)&a[0] = *(float4*)&As[kk][ty*4];
      *(float4*)&a[4] = *(float4*)&As[kk][64+ty*4];
      *(float4*)&b[0] = *(float4*)&Bs[kk][tx*4];
      *(float4*)&b[4] = *(float4*)&Bs[kk][64+tx*4];
      #pragma unroll
      for (int i=0;i<8;i++)
        #pragma unroll
        for (int j=0;j<8;j++)
          acc[i][j] = fmaf(a[i], b[j], acc[i][j]);
    }
    __syncthreads();
  }

  int bb = row0 >> 8;   // batch index (tile never crosses batch: 256%128==0)
  #pragma unroll
  for (int ih=0; ih<2; ih++)
    #pragma unroll
    for (int i=0;i<4;i++){
      int r = row0 + ih*64 + ty*4 + i;
      #pragma unroll
      for (int jh=0; jh<2; jh++){
        int cb = col0 + jh*64 + tx*4;
        float v[4];
        #pragma unroll
        for (int j=0;j<4;j++){
          v[j] = acc[ih*4+i][jh*4+j] + bias[cb+j];
          if (EPI==1) v[j] = gelu_f(v[j]);
        }
        if (EPI==2){
          const float* g = adap + (size_t)bb*ADA6 + gate_off + cb;
          float4 told = *(float4*)&Cout[(size_t)r*N + cb];
          v[0] = told.x + g[0]*v[0];
          v[1] = told.y + g[1]*v[1];
          v[2] = told.z + g[2]*v[2];
          v[3] = told.w + g[3]*v[3];
        }
        float4 sv = make_float4(v[0],v[1],v[2],v[3]);
        *(float4*)&Cout[(size_t)r*N + cb] = sv;
      }
    }
}

// ---------------- fused attention: one block per (b,h) ----------------
__launch_bounds__(256)
__global__ void k_attn(const float* __restrict__ qkv, float* __restrict__ o){
  int bh = blockIdx.x;
  int b = bh / NHEAD, h = bh % NHEAD;
  int tid = threadIdx.x;
  __shared__ float Ks[256][64];
  __shared__ float Vs[256][64];
  const float* base = qkv + (size_t)b*NPP*2304;
  #pragma unroll
  for (int p=0;p<16;p++){
    int e = tid + p*256;
    int r = e >> 4, c4 = e & 15;
    *(float4*)&Ks[r][c4*4] = *(const float4*)&base[(size_t)r*2304 + 768  + h*64 + c4*4];
    *(float4*)&Vs[r][c4*4] = *(const float4*)&base[(size_t)r*2304 + 1536 + h*64 + c4*4];
  }
  float q[64];
  const float* qrow = base + (size_t)tid*2304 + h*64;
  #pragma unroll
  for (int d4=0; d4<16; d4++) *(float4*)&q[d4*4] = *(const float4*)&qrow[d4*4];
  __syncthreads();

  float m = -1e30f, l = 0.f;
  float acc[64];
  #pragma unroll
  for (int d=0; d<64; d++) acc[d]=0.f;

  for (int k=0;k<256;k++){
    const float4* krow = (const float4*)&Ks[k][0];
    float s0=0.f,s1=0.f,s2=0.f,s3=0.f;
    #pragma unroll
    for (int d4=0; d4<16; d4++){
      float4 kv = krow[d4];
      s0 = fmaf(q[d4*4+0], kv.x, s0);
      s1 = fmaf(q[d4*4+1], kv.y, s1);
      s2 = fmaf(q[d4*4+2], kv.z, s2);
      s3 = fmaf(q[d4*4+3], kv.w, s3);
    }
    float s = ((s0+s1)+(s2+s3)) * 0.125f;
    float mn = fmaxf(m, s);
    float corr = __expf(m - mn);
    float p = __expf(s - mn);
    l = l*corr + p;
    m = mn;
    const float4* vrow = (const float4*)&Vs[k][0];
    #pragma unroll
    for (int d4=0; d4<16; d4++){
      float4 vv = vrow[d4];
      acc[d4*4+0] = fmaf(acc[d4*4+0], corr, p*vv.x);
      acc[d4*4+1] = fmaf(acc[d4*4+1], corr, p*vv.y);
      acc[d4*4+2] = fmaf(acc[d4*4+2], corr, p*vv.z);
      acc[d4*4+3] = fmaf(acc[d4*4+3], corr, p*vv.w);
    }
  }
  float inv = 1.f/l;
  float* orow = o + (size_t)(b*NPP + tid)*D + h*64;
  #pragma unroll
  for (int d4=0; d4<16; d4++){
    float4 sv = make_float4(acc[d4*4]*inv, acc[d4*4+1]*inv, acc[d4*4+2]*inv, acc[d4*4+3]*inv);
    *(float4*)&orow[d4*4] = sv;
  }
}

// ---------------- final linear + unpatchify ----------------
__global__ void k_final(const float* __restrict__ tokf, const float* __restrict__ w,
                        const float* __restrict__ bias, float* __restrict__ out){
  int idx = blockIdx.x*256 + threadIdx.x;   // NTOK*16
  int j = idx & 15, tk = idx >> 4;
  const float* a = tokf + (size_t)tk*D;
  float acc = bias[j];
  #pragma unroll 4
  for (int k=0;k<D;k++) acc = fmaf(a[k], w[k*16 + j], acc);
  int b = tk >> 8, n = tk & 255;
  int hi = n >> 4, wi = n & 15;
  int p1 = j >> 3, p2 = (j >> 2) & 1, c = j & 3;
  out[((size_t)(b*4 + c)*32 + hi*2 + p1)*32 + wi*2 + p2] = acc;
}

extern "C" void kernel_launch(void* const* d_in, const int* in_sizes, int n_in,
                              void* d_out, int out_size, void* d_ws, size_t ws_size,
                              hipStream_t stream){
  const float* x         = (const float*)d_in[0];
  const float* t         = (const float*)d_in[1];
  const float* conv_w    = (const float*)d_in[2];
  const float* conv_b    = (const float*)d_in[3];
  const float* tmlp_w1   = (const float*)d_in[4];
  const float* tmlp_b1   = (const float*)d_in[5];
  const float* tmlp_w2   = (const float*)d_in[6];
  const float* tmlp_b2   = (const float*)d_in[7];
  const float* cls_emb   = (const float*)d_in[8];
  const float* qkv_w     = (const float*)d_in[9];
  const float* qkv_b     = (const float*)d_in[10];
  const float* outp_w    = (const float*)d_in[11];
  const float* outp_b    = (const float*)d_in[12];
  const float* ada_w     = (const float*)d_in[13];
  const float* ada_b     = (const float*)d_in[14];
  const float* mlp_w1    = (const float*)d_in[15];
  const float* mlp_b1    = (const float*)d_in[16];
  const float* mlp_w2    = (const float*)d_in[17];
  const float* mlp_b2    = (const float*)d_in[18];
  const float* fin_ada_w = (const float*)d_in[19];
  const float* fin_ada_b = (const float*)d_in[20];
  const float* fin_lin_w = (const float*)d_in[21];
  const float* fin_lin_b = (const float*)d_in[22];
  const int*   label     = (const int*)d_in[23];
  float* out = (float*)d_out;

  float* ws   = (float*)d_ws;
  size_t o1   = (size_t)NTOK*D;          // 6291456 floats
  float* tok  = ws;
  float* hmod = tok  + o1;               // also reused as attention-output buffer
  float* big  = hmod + o1;               // NTOK*3072 (qkv then hmid)
  float* oatt = hmod;                    // alias: hmod dead after qkv GEMM
  float* c0   = big  + (size_t)NTOK*3072;
  float* chid = c0   + 32*D;
  float* cvec = chid + 32*3072;
  float* scv  = cvec + 32*D;
  float* ada  = scv  + 32*D;
  float* fada = ada  + 32*ADA6;

  k_patchify<<<NTOK*D/256, 256, 0, stream>>>(x, conv_w, conv_b, tok);
  k_timeembed<<<(NB*D)/256, 256, 0, stream>>>(t, c0);
  k_gemm_small<1><<<dim3(3072/256, NB), 256, 0, stream>>>(c0, tmlp_w1, tmlp_b1, chid, 3072, 768, nullptr, nullptr);
  k_gemm_small<2><<<dim3(768/256, NB), 256, 0, stream>>>(chid, tmlp_w2, tmlp_b2, cvec, 768, 3072, cls_emb, label);
  k_silu<<<(NB*D)/256, 256, 0, stream>>>(cvec, scv, NB*D);

  for (int i=0;i<NLAY;i++){
    const float* qw  = qkv_w  + (size_t)i*768*2304;
    const float* qb  = qkv_b  + (size_t)i*2304;
    const float* ow  = outp_w + (size_t)i*768*768;
    const float* ob  = outp_b + (size_t)i*768;
    const float* aw  = ada_w  + (size_t)i*768*ADA6;
    const float* ab  = ada_b  + (size_t)i*ADA6;
    const float* m1w = mlp_w1 + (size_t)i*768*3072;
    const float* m1b = mlp_b1 + (size_t)i*3072;
    const float* m2w = mlp_w2 + (size_t)i*3072*768;
    const float* m2b = mlp_b2 + (size_t)i*768;

    k_gemm_small<0><<<dim3(ADA6/256, NB), 256, 0, stream>>>(scv, aw, ab, ada, ADA6, 768, nullptr, nullptr);
    k_lnmod<<<NTOK, 256, 0, stream>>>(tok, ada, hmod, ADA6, 0, 768);
    k_gemm_tiled<0><<<dim3(2304/128, NTOK/128), 256, 0, stream>>>(hmod, qw, qb, big, 2304, 768, nullptr, 0);
    k_attn<<<NB*NHEAD, 256, 0, stream>>>(big, oatt);
    k_gemm_tiled<2><<<dim3(768/128, NTOK/128), 256, 0, stream>>>(oatt, ow, ob, tok, 768, 768, ada, 1536);
    k_lnmod<<<NTOK, 256, 0, stream>>>(tok, ada, hmod, ADA6, 2304, 3072);
    k_gemm_tiled<1><<<dim3(3072/128, NTOK/128), 256, 0, stream>>>(hmod, m1w, m1b, big, 3072, 768, nullptr, 0);
    k_gemm_tiled<2><<<dim3(768/128, NTOK/128), 256, 0, stream>>>(big, m2w, m2b, tok, 768, 3072, ada, 3840);
  }

  k_gemm_small<0><<<dim3(1536/256, NB), 256, 0, stream>>>(scv, fin_ada_w, fin_ada_b, fada, 1536, 768, nullptr, nullptr);
  k_lnmod<<<NTOK, 256, 0, stream>>>(tok, fada, hmod, 1536, 0, 768);
  k_final<<<NTOK*16/256, 256, 0, stream>>>(hmod, fin_lin_w, fin_lin_b, out);
}

// Round 3
// 8990.401 us; speedup vs baseline: 2.6502x; 2.6502x over previous
//
#include <hip/hip_runtime.h>
#include <math.h>

#define NB    32
#define D     768
#define NPP   256
#define NTOK  (NB*NPP)   // 8192
#define NHEAD 12
#define NLAY  12
#define ADA6  4608

typedef unsigned short bf16_t;
typedef __attribute__((ext_vector_type(8))) short  bf16x8;
typedef __attribute__((ext_vector_type(4))) float  f32x4;

__device__ __forceinline__ float silu_f(float x){ return x / (1.f + __expf(-x)); }
__device__ __forceinline__ float gelu_f(float x){ return 0.5f*x*(1.f + erff(x*0.7071067811865476f)); }

// bf16 bit helpers (RNE), avoids hip_bf16 API: buffers are ushort
__device__ __forceinline__ bf16_t f2bf(float f){
  unsigned int u; __builtin_memcpy(&u, &f, 4);
  unsigned int r = (u + 0x7fffu + ((u >> 16) & 1u)) >> 16;
  return (bf16_t)r;
}
__device__ __forceinline__ float bf2f(unsigned int bits){
  unsigned int u = bits << 16; float f; __builtin_memcpy(&f, &u, 4); return f;
}

__device__ __forceinline__ void stf(float* p, float v){ *p = v; }
__device__ __forceinline__ void stf(bf16_t* p, float v){ *p = f2bf(v); }

#define GLD16(gsrc, ldst) __builtin_amdgcn_global_load_lds( \
    (const __attribute__((address_space(1))) void*)(gsrc), \
    (__attribute__((address_space(3))) void*)(ldst), 16, 0, 0)

// ---------------- patchify + pos-embed (fp32 out) ----------------
__global__ void k_patchify(const float* __restrict__ x, const float* __restrict__ cw,
                           const float* __restrict__ cb, float* __restrict__ tok){
  int idx = blockIdx.x*256 + threadIdx.x;        // over NTOK*D
  int d = idx % D, tk = idx / D;
  int b = tk >> 8, n = tk & 255;
  int hi = n >> 4, wi = n & 15;
  float acc = cb[d];
  const float* xb = x + (size_t)b*4*32*32;
  #pragma unroll
  for (int c=0;c<4;c++)
    #pragma unroll
    for (int p1=0;p1<2;p1++)
      #pragma unroll
      for (int p2=0;p2<2;p2++){
        float xv = xb[(c*32 + hi*2+p1)*32 + wi*2+p2];
        acc = fmaf(xv, cw[d*16 + c*4 + p1*2 + p2], acc);
      }
  int i2 = d >> 1;
  float ang = (float)n * powf(10000.f, -(float)(2*i2)/768.f);
  acc += (d & 1) ? cosf(ang) : sinf(ang);
  tok[idx] = acc;
}

// ---------------- time embedding ----------------
__global__ void k_timeembed(const float* __restrict__ t, float* __restrict__ c0){
  int idx = blockIdx.x*256 + threadIdx.x;        // 32*768
  if (idx >= NB*D) return;
  int b = idx / D, d = idx % D;
  int j = (d < 384) ? d : d - 384;
  float emb = expf((float)j * (-logf(10000.f)/383.f));
  float e = t[b]*emb;
  c0[idx] = (d < 384) ? sinf(e) : cosf(e);
}

__global__ void k_silu(const float* __restrict__ in, float* __restrict__ out, int n){
  int i = blockIdx.x*256 + threadIdx.x;
  if (i < n) out[i] = silu_f(in[i]);
}

// ---------------- small GEMM (M<=32): thread per output, fp32 ----------------
template<int EPI>
__global__ void k_gemm_small(const float* __restrict__ A, const float* __restrict__ W,
                             const float* __restrict__ bias, float* __restrict__ Cout,
                             int N, int K,
                             const float* __restrict__ cls, const int* __restrict__ label){
  int n = blockIdx.x*256 + threadIdx.x;
  int m = blockIdx.y;
  if (n >= N) return;
  const float* a = A + (size_t)m*K;
  float acc = bias[n];
  #pragma unroll 4
  for (int k=0;k<K;k++) acc = fmaf(a[k], W[(size_t)k*N + n], acc);
  if (EPI==1) acc = silu_f(acc);
  if (EPI==2) acc += cls[(size_t)label[m]*D + n];
  Cout[(size_t)m*N + n] = acc;
}

// ---------------- fused LayerNorm + adaLN modulate; OT = float or bf16 ----------------
template<typename OT>
__global__ void k_lnmod(const float* __restrict__ tok, const float* __restrict__ ada,
                        OT* __restrict__ outb, int ada_stride, int sh_off, int sc_off){
  int tk = blockIdx.x, tid = threadIdx.x;
  int b = tk >> 8;
  const float* row = tok + (size_t)tk*D;
  float x0 = row[tid], x1 = row[tid+256], x2 = row[tid+512];
  float s1 = x0+x1+x2;
  float s2 = x0*x0 + x1*x1 + x2*x2;
  #pragma unroll
  for (int off=32; off; off>>=1){
    s1 += __shfl_xor(s1, off);
    s2 += __shfl_xor(s2, off);
  }
  __shared__ float r1[4], r2[4];
  int wid = tid >> 6, lane = tid & 63;
  if (lane==0){ r1[wid]=s1; r2[wid]=s2; }
  __syncthreads();
  float t1 = r1[0]+r1[1]+r1[2]+r1[3];
  float t2 = r2[0]+r2[1]+r2[2]+r2[3];
  float mean = t1*(1.f/768.f);
  float var  = t2*(1.f/768.f) - mean*mean;
  float rstd = rsqrtf(var + 1e-6f);
  const float* sh = ada + (size_t)b*ada_stride + sh_off;
  const float* sc = ada + (size_t)b*ada_stride + sc_off;
  OT* orow = outb + (size_t)tk*D;
  stf(&orow[tid    ], (x0-mean)*rstd*(1.f+sc[tid    ]) + sh[tid    ]);
  stf(&orow[tid+256], (x1-mean)*rstd*(1.f+sc[tid+256]) + sh[tid+256]);
  stf(&orow[tid+512], (x2-mean)*rstd*(1.f+sc[tid+512]) + sh[tid+512]);
}

// ---------------- weight fp32 [K][N] -> bf16 [N][K] transpose ----------------
__global__ void k_w2bf16t(const float* __restrict__ W, bf16_t* __restrict__ Wt,
                          int K, int N){
  __shared__ float t[32][33];
  int n0 = blockIdx.x*32, k0 = blockIdx.y*32;
  int c = threadIdx.x & 31, r0 = threadIdx.x >> 5;     // r0 in 0..7
  #pragma unroll
  for (int rr=0; rr<4; rr++){
    int r = r0 + rr*8;
    t[r][c] = W[(size_t)(k0+r)*N + n0 + c];
  }
  __syncthreads();
  #pragma unroll
  for (int rr=0; rr<4; rr++){
    int r = r0 + rr*8;
    Wt[(size_t)(n0+r)*K + k0 + c] = f2bf(t[c][r]);
  }
}

// ---------------- bf16 MFMA GEMM: C[M,N] = epi(A[M,K] @ Wt[N,K]^T + bias) ----------------
// 128x128 tile, BK=32, 4 waves (2x2 of 64x64), mfma_f32_16x16x32_bf16,
// global_load_lds width-16 staging (m97 structure).
// EPI: 0 = bf16 store, 1 = gelu -> bf16 store, 2 = tokio += gate * val (fp32)
template<int EPI>
__launch_bounds__(256)
__global__ void k_gemm_mfma(const bf16_t* __restrict__ A, const bf16_t* __restrict__ Wt,
                            const float* __restrict__ bias, bf16_t* __restrict__ Cout,
                            float* __restrict__ tokio, int N, int K,
                            const float* __restrict__ adap, int gate_off){
  __shared__ bf16_t As[128*32];
  __shared__ bf16_t Bs[128*32];
  int tid = threadIdx.x;
  int w = tid >> 6, lane = tid & 63;
  int col0 = blockIdx.x*128, row0 = blockIdx.y*128;
  int wm = w >> 1, wn = w & 1;

  int sRow = lane >> 2;          // 0..15 row within 16-row chunk
  int sK   = (lane & 3) * 8;     // 0,8,16,24 (elements)

  f32x4 acc[4][4];
  #pragma unroll
  for (int i=0;i<4;i++)
    #pragma unroll
    for (int j=0;j<4;j++)
      acc[i][j] = (f32x4){0.f,0.f,0.f,0.f};

  const bf16_t* Aptr = A  + (size_t)row0*K;
  const bf16_t* Bptr = Wt + (size_t)col0*K;
  int fr = lane & 15, g = lane >> 4;

  for (int kt=0; kt<K; kt+=32){
    #pragma unroll
    for (int r=0;r<2;r++){
      int ch = w*2 + r;                 // 0..7, wave-uniform
      int rowi = ch*16 + sRow;
      GLD16(Aptr + (size_t)rowi*K + kt + sK, As + ch*512);
      GLD16(Bptr + (size_t)rowi*K + kt + sK, Bs + ch*512);
    }
    __syncthreads();
    bf16x8 af[4], bfr[4];
    #pragma unroll
    for (int i=0;i<4;i++)
      af[i] = *(const bf16x8*)&As[(wm*64 + i*16 + fr)*32 + g*8];
    #pragma unroll
    for (int j=0;j<4;j++)
      bfr[j] = *(const bf16x8*)&Bs[(wn*64 + j*16 + fr)*32 + g*8];
    #pragma unroll
    for (int i=0;i<4;i++)
      #pragma unroll
      for (int j=0;j<4;j++)
        acc[i][j] = __builtin_amdgcn_mfma_f32_16x16x32_bf16(af[i], bfr[j], acc[i][j], 0, 0, 0);
    __syncthreads();
  }

  // epilogue: C/D layout col = lane&15, row = (lane>>4)*4 + reg  [m89-verified]
  int g4 = g*4;
  int bb = row0 >> 8;
  #pragma unroll
  for (int i=0;i<4;i++){
    #pragma unroll
    for (int j=0;j<4;j++){
      int c = col0 + wn*64 + j*16 + fr;
      float bv = bias[c];
      float gv = 0.f;
      if (EPI==2) gv = adap[(size_t)bb*ADA6 + gate_off + c];
      #pragma unroll
      for (int v=0; v<4; v++){
        int r = row0 + wm*64 + i*16 + g4 + v;
        float val = acc[i][j][v] + bv;
        if (EPI==0) Cout[(size_t)r*N + c] = f2bf(val);
        if (EPI==1) Cout[(size_t)r*N + c] = f2bf(gelu_f(val));
        if (EPI==2) tokio[(size_t)r*N + c] += gv*val;
      }
    }
  }
}

// ---------------- fused attention: one block per (b,h), bf16 in/out ----------------
__launch_bounds__(256)
__global__ void k_attn(const bf16_t* __restrict__ qkv, bf16_t* __restrict__ o){
  int bh = blockIdx.x;
  int b = bh / NHEAD, h = bh % NHEAD;
  int tid = threadIdx.x;
  __shared__ float Ks[256][64];
  __shared__ float Vs[256][64];
  const bf16_t* base = qkv + (size_t)b*NPP*2304;
  #pragma unroll
  for (int p=0;p<8;p++){
    int gidx = p*256 + tid;            // 0..2047 granules of 8 bf16
    int r = gidx >> 3, c8 = gidx & 7;
    uint4 kv = *(const uint4*)(base + (size_t)r*2304 + 768  + h*64 + c8*8);
    uint4 vv = *(const uint4*)(base + (size_t)r*2304 + 1536 + h*64 + c8*8);
    float* kd = &Ks[r][c8*8];
    float* vd = &Vs[r][c8*8];
    kd[0]=bf2f(kv.x&0xffff); kd[1]=bf2f(kv.x>>16); kd[2]=bf2f(kv.y&0xffff); kd[3]=bf2f(kv.y>>16);
    kd[4]=bf2f(kv.z&0xffff); kd[5]=bf2f(kv.z>>16); kd[6]=bf2f(kv.w&0xffff); kd[7]=bf2f(kv.w>>16);
    vd[0]=bf2f(vv.x&0xffff); vd[1]=bf2f(vv.x>>16); vd[2]=bf2f(vv.y&0xffff); vd[3]=bf2f(vv.y>>16);
    vd[4]=bf2f(vv.z&0xffff); vd[5]=bf2f(vv.z>>16); vd[6]=bf2f(vv.w&0xffff); vd[7]=bf2f(vv.w>>16);
  }
  float q[64];
  const bf16_t* qrow = base + (size_t)tid*2304 + h*64;
  #pragma unroll
  for (int d8=0; d8<8; d8++){
    uint4 qv = *(const uint4*)(qrow + d8*8);
    float* qd = &q[d8*8];
    qd[0]=bf2f(qv.x&0xffff)*0.125f; qd[1]=bf2f(qv.x>>16)*0.125f;
    qd[2]=bf2f(qv.y&0xffff)*0.125f; qd[3]=bf2f(qv.y>>16)*0.125f;
    qd[4]=bf2f(qv.z&0xffff)*0.125f; qd[5]=bf2f(qv.z>>16)*0.125f;
    qd[6]=bf2f(qv.w&0xffff)*0.125f; qd[7]=bf2f(qv.w>>16)*0.125f;
  }
  __syncthreads();

  float m = -1e30f, l = 0.f;
  float acc[64];
  #pragma unroll
  for (int d=0; d<64; d++) acc[d]=0.f;

  for (int k=0;k<256;k++){
    const float4* krow = (const float4*)&Ks[k][0];
    float s0=0.f,s1=0.f,s2=0.f,s3=0.f;
    #pragma unroll
    for (int d4=0; d4<16; d4++){
      float4 kv = krow[d4];
      s0 = fmaf(q[d4*4+0], kv.x, s0);
      s1 = fmaf(q[d4*4+1], kv.y, s1);
      s2 = fmaf(q[d4*4+2], kv.z, s2);
      s3 = fmaf(q[d4*4+3], kv.w, s3);
    }
    float s = (s0+s1)+(s2+s3);
    float mn = fmaxf(m, s);
    float corr = __expf(m - mn);
    float p = __expf(s - mn);
    l = l*corr + p;
    m = mn;
    const float4* vrow = (const float4*)&Vs[k][0];
    #pragma unroll
    for (int d4=0; d4<16; d4++){
      float4 vv = vrow[d4];
      acc[d4*4+0] = fmaf(acc[d4*4+0], corr, p*vv.x);
      acc[d4*4+1] = fmaf(acc[d4*4+1], corr, p*vv.y);
      acc[d4*4+2] = fmaf(acc[d4*4+2], corr, p*vv.z);
      acc[d4*4+3] = fmaf(acc[d4*4+3], corr, p*vv.w);
    }
  }
  float inv = 1.f/l;
  bf16_t* orow = o + (size_t)(b*NPP + tid)*D + h*64;
  #pragma unroll
  for (int d8=0; d8<8; d8++){
    uint4 sv;
    sv.x = (unsigned)f2bf(acc[d8*8+0]*inv) | ((unsigned)f2bf(acc[d8*8+1]*inv)<<16);
    sv.y = (unsigned)f2bf(acc[d8*8+2]*inv) | ((unsigned)f2bf(acc[d8*8+3]*inv)<<16);
    sv.z = (unsigned)f2bf(acc[d8*8+4]*inv) | ((unsigned)f2bf(acc[d8*8+5]*inv)<<16);
    sv.w = (unsigned)f2bf(acc[d8*8+6]*inv) | ((unsigned)f2bf(acc[d8*8+7]*inv)<<16);
    *(uint4*)(orow + d8*8) = sv;
  }
}

// ---------------- final linear + unpatchify ----------------
__global__ void k_final(const float* __restrict__ tokf, const float* __restrict__ w,
                        const float* __restrict__ bias, float* __restrict__ out){
  int idx = blockIdx.x*256 + threadIdx.x;   // NTOK*16
  int j = idx & 15, tk = idx >> 4;
  const float* a = tokf + (size_t)tk*D;
  float acc = bias[j];
  #pragma unroll 4
  for (int k=0;k<D;k++) acc = fmaf(a[k], w[k*16 + j], acc);
  int b = tk >> 8, n = tk & 255;
  int hi = n >> 4, wi = n & 15;
  int p1 = j >> 3, p2 = (j >> 2) & 1, c = j & 3;
  out[((size_t)(b*4 + c)*32 + hi*2 + p1)*32 + wi*2 + p2] = acc;
}

extern "C" void kernel_launch(void* const* d_in, const int* in_sizes, int n_in,
                              void* d_out, int out_size, void* d_ws, size_t ws_size,
                              hipStream_t stream){
  const float* x         = (const float*)d_in[0];
  const float* t         = (const float*)d_in[1];
  const float* conv_w    = (const float*)d_in[2];
  const float* conv_b    = (const float*)d_in[3];
  const float* tmlp_w1   = (const float*)d_in[4];
  const float* tmlp_b1   = (const float*)d_in[5];
  const float* tmlp_w2   = (const float*)d_in[6];
  const float* tmlp_b2   = (const float*)d_in[7];
  const float* cls_emb   = (const float*)d_in[8];
  const float* qkv_w     = (const float*)d_in[9];
  const float* qkv_b     = (const float*)d_in[10];
  const float* outp_w    = (const float*)d_in[11];
  const float* outp_b    = (const float*)d_in[12];
  const float* ada_w     = (const float*)d_in[13];
  const float* ada_b     = (const float*)d_in[14];
  const float* mlp_w1    = (const float*)d_in[15];
  const float* mlp_b1    = (const float*)d_in[16];
  const float* mlp_w2    = (const float*)d_in[17];
  const float* mlp_b2    = (const float*)d_in[18];
  const float* fin_ada_w = (const float*)d_in[19];
  const float* fin_ada_b = (const float*)d_in[20];
  const float* fin_lin_w = (const float*)d_in[21];
  const float* fin_lin_b = (const float*)d_in[22];
  const int*   label     = (const int*)d_in[23];
  float* out = (float*)d_out;

  // ---- workspace layout (bytes, 256-aligned blocks) ----
  char* wp = (char*)d_ws;
  float*  tok   = (float*)wp;              wp += (size_t)NTOK*D*4;        // 25.2MB fp32
  bf16_t* bigb  = (bf16_t*)wp;             wp += (size_t)NTOK*3072*2;     // 50.3MB: qkv out / hmid / final ln (as float)
  bf16_t* hmodb = (bf16_t*)wp;             wp += (size_t)NTOK*D*2;        // 12.6MB
  bf16_t* oattb = (bf16_t*)wp;             wp += (size_t)NTOK*D*2;        // 12.6MB
  bf16_t* wqT   = (bf16_t*)wp;             wp += (size_t)2304*768*2;
  bf16_t* woT   = (bf16_t*)wp;             wp += (size_t)768*768*2;
  bf16_t* w1T   = (bf16_t*)wp;             wp += (size_t)3072*768*2;
  bf16_t* w2T   = (bf16_t*)wp;             wp += (size_t)768*3072*2;
  float*  c0    = (float*)wp;              wp += (size_t)NB*D*4;
  float*  chid  = (float*)wp;              wp += (size_t)NB*3072*4;
  float*  cvec  = (float*)wp;              wp += (size_t)NB*D*4;
  float*  scv   = (float*)wp;              wp += (size_t)NB*D*4;
  float*  ada   = (float*)wp;              wp += (size_t)NB*ADA6*4;
  float*  fada  = (float*)wp;              wp += (size_t)NB*1536*4;
  float*  hmodF = (float*)bigb;            // final LN output aliases bigb

  k_patchify<<<NTOK*D/256, 256, 0, stream>>>(x, conv_w, conv_b, tok);
  k_timeembed<<<(NB*D)/256, 256, 0, stream>>>(t, c0);
  k_gemm_small<1><<<dim3(3072/256, NB), 256, 0, stream>>>(c0, tmlp_w1, tmlp_b1, chid, 3072, 768, nullptr, nullptr);
  k_gemm_small<2><<<dim3(768/256, NB), 256, 0, stream>>>(chid, tmlp_w2, tmlp_b2, cvec, 768, 3072, cls_emb, label);
  k_silu<<<(NB*D)/256, 256, 0, stream>>>(cvec, scv, NB*D);

  for (int i=0;i<NLAY;i++){
    const float* qw  = qkv_w  + (size_t)i*768*2304;
    const float* qb  = qkv_b  + (size_t)i*2304;
    const float* ow  = outp_w + (size_t)i*768*768;
    const float* ob  = outp_b + (size_t)i*768;
    const float* aw  = ada_w  + (size_t)i*768*ADA6;
    const float* ab  = ada_b  + (size_t)i*ADA6;
    const float* m1w = mlp_w1 + (size_t)i*768*3072;
    const float* m1b = mlp_b1 + (size_t)i*3072;
    const float* m2w = mlp_w2 + (size_t)i*3072*768;
    const float* m2b = mlp_b2 + (size_t)i*768;

    // per-layer weight convert+transpose: fp32 [K][N] -> bf16 [N][K]
    k_w2bf16t<<<dim3(2304/32,  768/32), 256, 0, stream>>>(qw,  wqT, 768, 2304);
    k_w2bf16t<<<dim3( 768/32,  768/32), 256, 0, stream>>>(ow,  woT, 768, 768);
    k_w2bf16t<<<dim3(3072/32,  768/32), 256, 0, stream>>>(m1w, w1T, 768, 3072);
    k_w2bf16t<<<dim3( 768/32, 3072/32), 256, 0, stream>>>(m2w, w2T, 3072, 768);

    k_gemm_small<0><<<dim3(ADA6/256, NB), 256, 0, stream>>>(scv, aw, ab, ada, ADA6, 768, nullptr, nullptr);
    k_lnmod<bf16_t><<<NTOK, 256, 0, stream>>>(tok, ada, hmodb, ADA6, 0, 768);
    k_gemm_mfma<0><<<dim3(2304/128, NTOK/128), 256, 0, stream>>>(hmodb, wqT, qb, bigb, nullptr, 2304, 768, nullptr, 0);
    k_attn<<<NB*NHEAD, 256, 0, stream>>>(bigb, oattb);
    k_gemm_mfma<2><<<dim3( 768/128, NTOK/128), 256, 0, stream>>>(oattb, woT, ob, nullptr, tok, 768, 768, ada, 1536);
    k_lnmod<bf16_t><<<NTOK, 256, 0, stream>>>(tok, ada, hmodb, ADA6, 2304, 3072);
    k_gemm_mfma<1><<<dim3(3072/128, NTOK/128), 256, 0, stream>>>(hmodb, w1T, m1b, bigb, nullptr, 3072, 768, nullptr, 0);
    k_gemm_mfma<2><<<dim3( 768/128, NTOK/128), 256, 0, stream>>>(bigb, w2T, m2b, nullptr, tok, 768, 3072, ada, 3840);
  }

  k_gemm_small<0><<<dim3(1536/256, NB), 256, 0, stream>>>(scv, fin_ada_w, fin_ada_b, fada, 1536, 768, nullptr, nullptr);
  k_lnmod<float><<<NTOK, 256, 0, stream>>>(tok, fada, hmodF, 1536, 0, 768);
  k_final<<<NTOK*16/256, 256, 0, stream>>>(hmodF, fin_lin_w, fin_lin_b, out);
}

// Round 4
// 8376.946 us; speedup vs baseline: 2.8443x; 1.0732x over previous
//
#include <hip/hip_runtime.h>
#include <math.h>

#define NB    32
#define D     768
#define NPP   256
#define NTOK  (NB*NPP)   // 8192
#define NHEAD 12
#define NLAY  12
#define ADA6  4608
#define ADATOT (NLAY*ADA6)   // 55296

typedef unsigned short bf16_t;
typedef __attribute__((ext_vector_type(8))) short  bf16x8;
typedef __attribute__((ext_vector_type(4))) float  f32x4;

__device__ __forceinline__ float silu_f(float x){ return x / (1.f + __expf(-x)); }
__device__ __forceinline__ float gelu_f(float x){ return 0.5f*x*(1.f + erff(x*0.7071067811865476f)); }

// bf16 bit helpers (RNE)
__device__ __forceinline__ bf16_t f2bf(float f){
  unsigned int u; __builtin_memcpy(&u, &f, 4);
  unsigned int r = (u + 0x7fffu + ((u >> 16) & 1u)) >> 16;
  return (bf16_t)r;
}
__device__ __forceinline__ float bf2f(unsigned int bits){
  unsigned int u = bits << 16; float f; __builtin_memcpy(&f, &u, 4); return f;
}

__device__ __forceinline__ void stf(float* p, float v){ *p = v; }
__device__ __forceinline__ void stf(bf16_t* p, float v){ *p = f2bf(v); }

#define GLD16(gsrc, ldst) __builtin_amdgcn_global_load_lds( \
    (const __attribute__((address_space(1))) void*)(gsrc), \
    (__attribute__((address_space(3))) void*)(ldst), 16, 0, 0)

// ---------------- patchify + pos-embed (fp32 out) ----------------
__global__ void k_patchify(const float* __restrict__ x, const float* __restrict__ cw,
                           const float* __restrict__ cb, float* __restrict__ tok){
  int idx = blockIdx.x*256 + threadIdx.x;        // over NTOK*D
  int d = idx % D, tk = idx / D;
  int b = tk >> 8, n = tk & 255;
  int hi = n >> 4, wi = n & 15;
  float acc = cb[d];
  const float* xb = x + (size_t)b*4*32*32;
  #pragma unroll
  for (int c=0;c<4;c++)
    #pragma unroll
    for (int p1=0;p1<2;p1++)
      #pragma unroll
      for (int p2=0;p2<2;p2++){
        float xv = xb[(c*32 + hi*2+p1)*32 + wi*2+p2];
        acc = fmaf(xv, cw[d*16 + c*4 + p1*2 + p2], acc);
      }
  int i2 = d >> 1;
  float ang = (float)n * powf(10000.f, -(float)(2*i2)/768.f);
  acc += (d & 1) ? cosf(ang) : sinf(ang);
  tok[idx] = acc;
}

// ---------------- time embedding ----------------
__global__ void k_timeembed(const float* __restrict__ t, float* __restrict__ c0){
  int idx = blockIdx.x*256 + threadIdx.x;        // 32*768
  if (idx >= NB*D) return;
  int b = idx / D, d = idx % D;
  int j = (d < 384) ? d : d - 384;
  float emb = expf((float)j * (-logf(10000.f)/383.f));
  float e = t[b]*emb;
  c0[idx] = (d < 384) ? sinf(e) : cosf(e);
}

__global__ void k_silu(const float* __restrict__ in, float* __restrict__ out, int n){
  int i = blockIdx.x*256 + threadIdx.x;
  if (i < n) out[i] = silu_f(in[i]);
}

// ---------------- skinny GEMM (M=32): 64 cols x 4 K-slices per block ----------------
// Cout[m][ng] = epi( sum_k A[m][k] * W[lay*K*Nper + k*Nper + n] + bias[ng] )
// where lay = ng/Nper, n = ng%Nper. EPI: 0 plain, 1 silu, 2 +cls[label[m]][n]
template<int EPI>
__launch_bounds__(256)
__global__ void k_gemm_skinny(const float* __restrict__ A, const float* __restrict__ W,
                              const float* __restrict__ bias, float* __restrict__ Cout,
                              int Ntot, int Nper, int K,
                              const float* __restrict__ cls, const int* __restrict__ label){
  __shared__ float Als[3072];
  __shared__ float red[4][64];
  int tid = threadIdx.x;
  int m = blockIdx.y;
  int j = tid & 63;
  int ng = blockIdx.x*64 + j;
  int ks = tid >> 6;
  int lay = ng / Nper;
  int n   = ng - lay*Nper;
  const float* arow = A + (size_t)m*K;
  for (int k = tid; k < K; k += 256) Als[k] = arow[k];
  __syncthreads();
  const float* wcol = W + (size_t)lay*K*Nper + n;
  int kq = K >> 2;
  int k0 = ks*kq;
  float acc = 0.f;
  #pragma unroll 4
  for (int kk = 0; kk < kq; kk++){
    int k = k0 + kk;
    acc = fmaf(Als[k], wcol[(size_t)k*Nper], acc);
  }
  red[ks][j] = acc;
  __syncthreads();
  if (ks == 0){
    float s = red[0][j] + red[1][j] + red[2][j] + red[3][j] + bias[ng];
    if (EPI==1) s = silu_f(s);
    if (EPI==2) s += cls[(size_t)label[m]*D + n];
    Cout[(size_t)m*Ntot + ng] = s;
  }
}

// ---------------- fused LayerNorm + adaLN modulate; OT = float or bf16 ----------------
template<typename OT>
__global__ void k_lnmod(const float* __restrict__ tok, const float* __restrict__ ada,
                        OT* __restrict__ outb, int ada_stride, int sh_off, int sc_off){
  int tk = blockIdx.x, tid = threadIdx.x;
  int b = tk >> 8;
  const float* row = tok + (size_t)tk*D;
  float x0 = row[tid], x1 = row[tid+256], x2 = row[tid+512];
  float s1 = x0+x1+x2;
  float s2 = x0*x0 + x1*x1 + x2*x2;
  #pragma unroll
  for (int off=32; off; off>>=1){
    s1 += __shfl_xor(s1, off);
    s2 += __shfl_xor(s2, off);
  }
  __shared__ float r1[4], r2[4];
  int wid = tid >> 6, lane = tid & 63;
  if (lane==0){ r1[wid]=s1; r2[wid]=s2; }
  __syncthreads();
  float t1 = r1[0]+r1[1]+r1[2]+r1[3];
  float t2 = r2[0]+r2[1]+r2[2]+r2[3];
  float mean = t1*(1.f/768.f);
  float var  = t2*(1.f/768.f) - mean*mean;
  float rstd = rsqrtf(var + 1e-6f);
  const float* sh = ada + (size_t)b*ada_stride + sh_off;
  const float* sc = ada + (size_t)b*ada_stride + sc_off;
  OT* orow = outb + (size_t)tk*D;
  stf(&orow[tid    ], (x0-mean)*rstd*(1.f+sc[tid    ]) + sh[tid    ]);
  stf(&orow[tid+256], (x1-mean)*rstd*(1.f+sc[tid+256]) + sh[tid+256]);
  stf(&orow[tid+512], (x2-mean)*rstd*(1.f+sc[tid+512]) + sh[tid+512]);
}

// ---------------- weight fp32 [K][N] -> bf16 [N][K] transpose ----------------
__global__ void k_w2bf16t(const float* __restrict__ W, bf16_t* __restrict__ Wt,
                          int K, int N){
  __shared__ float t[32][33];
  int n0 = blockIdx.x*32, k0 = blockIdx.y*32;
  int c = threadIdx.x & 31, r0 = threadIdx.x >> 5;     // r0 in 0..7
  #pragma unroll
  for (int rr=0; rr<4; rr++){
    int r = r0 + rr*8;
    t[r][c] = W[(size_t)(k0+r)*N + n0 + c];
  }
  __syncthreads();
  #pragma unroll
  for (int rr=0; rr<4; rr++){
    int r = r0 + rr*8;
    Wt[(size_t)(n0+r)*K + k0 + c] = f2bf(t[c][r]);
  }
}

// ---------------- bf16 MFMA GEMM: C[M,N] = epi(A[M,K] @ Wt[N,K]^T + bias) ----------------
// 128x128 tile, BK=32, 4 waves (2x2 of 64x64), mfma_f32_16x16x32_bf16.
// EPI: 0 = bf16 store, 1 = gelu -> bf16 store, 2 = tokio += gate * val (fp32)
template<int EPI>
__launch_bounds__(256)
__global__ void k_gemm_mfma(const bf16_t* __restrict__ A, const bf16_t* __restrict__ Wt,
                            const float* __restrict__ bias, bf16_t* __restrict__ Cout,
                            float* __restrict__ tokio, int N, int K,
                            const float* __restrict__ adap, int ada_ld, int gate_off){
  __shared__ bf16_t As[128*32];
  __shared__ bf16_t Bs[128*32];
  int tid = threadIdx.x;
  int w = tid >> 6, lane = tid & 63;
  int col0 = blockIdx.x*128, row0 = blockIdx.y*128;
  int wm = w >> 1, wn = w & 1;

  int sRow = lane >> 2;          // 0..15 row within 16-row chunk
  int sK   = (lane & 3) * 8;     // 0,8,16,24 (elements)

  f32x4 acc[4][4];
  #pragma unroll
  for (int i=0;i<4;i++)
    #pragma unroll
    for (int j=0;j<4;j++)
      acc[i][j] = (f32x4){0.f,0.f,0.f,0.f};

  const bf16_t* Aptr = A  + (size_t)row0*K;
  const bf16_t* Bptr = Wt + (size_t)col0*K;
  int fr = lane & 15, g = lane >> 4;

  for (int kt=0; kt<K; kt+=32){
    #pragma unroll
    for (int r=0;r<2;r++){
      int ch = w*2 + r;                 // 0..7, wave-uniform
      int rowi = ch*16 + sRow;
      GLD16(Aptr + (size_t)rowi*K + kt + sK, As + ch*512);
      GLD16(Bptr + (size_t)rowi*K + kt + sK, Bs + ch*512);
    }
    __syncthreads();
    bf16x8 af[4], bfr[4];
    #pragma unroll
    for (int i=0;i<4;i++)
      af[i] = *(const bf16x8*)&As[(wm*64 + i*16 + fr)*32 + g*8];
    #pragma unroll
    for (int j=0;j<4;j++)
      bfr[j] = *(const bf16x8*)&Bs[(wn*64 + j*16 + fr)*32 + g*8];
    #pragma unroll
    for (int i=0;i<4;i++)
      #pragma unroll
      for (int j=0;j<4;j++)
        acc[i][j] = __builtin_amdgcn_mfma_f32_16x16x32_bf16(af[i], bfr[j], acc[i][j], 0, 0, 0);
    __syncthreads();
  }

  // epilogue: C/D layout col = lane&15, row = (lane>>4)*4 + reg  [m89-verified]
  int g4 = g*4;
  int bb = row0 >> 8;
  #pragma unroll
  for (int i=0;i<4;i++){
    #pragma unroll
    for (int j=0;j<4;j++){
      int c = col0 + wn*64 + j*16 + fr;
      float bv = bias[c];
      float gv = 0.f;
      if (EPI==2) gv = adap[(size_t)bb*ada_ld + gate_off + c];
      #pragma unroll
      for (int v=0; v<4; v++){
        int r = row0 + wm*64 + i*16 + g4 + v;
        float val = acc[i][j][v] + bv;
        if (EPI==0) Cout[(size_t)r*N + c] = f2bf(val);
        if (EPI==1) Cout[(size_t)r*N + c] = f2bf(gelu_f(val));
        if (EPI==2) tokio[(size_t)r*N + c] += gv*val;
      }
    }
  }
}

// ---------------- fused attention: one block per (b,h), bf16 in/out ----------------
__launch_bounds__(256)
__global__ void k_attn(const bf16_t* __restrict__ qkv, bf16_t* __restrict__ o){
  int bh = blockIdx.x;
  int b = bh / NHEAD, h = bh % NHEAD;
  int tid = threadIdx.x;
  __shared__ float Ks[256][64];
  __shared__ float Vs[256][64];
  const bf16_t* base = qkv + (size_t)b*NPP*2304;
  #pragma unroll
  for (int p=0;p<8;p++){
    int gidx = p*256 + tid;            // 0..2047 granules of 8 bf16
    int r = gidx >> 3, c8 = gidx & 7;
    uint4 kv = *(const uint4*)(base + (size_t)r*2304 + 768  + h*64 + c8*8);
    uint4 vv = *(const uint4*)(base + (size_t)r*2304 + 1536 + h*64 + c8*8);
    float* kd = &Ks[r][c8*8];
    float* vd = &Vs[r][c8*8];
    kd[0]=bf2f(kv.x&0xffff); kd[1]=bf2f(kv.x>>16); kd[2]=bf2f(kv.y&0xffff); kd[3]=bf2f(kv.y>>16);
    kd[4]=bf2f(kv.z&0xffff); kd[5]=bf2f(kv.z>>16); kd[6]=bf2f(kv.w&0xffff); kd[7]=bf2f(kv.w>>16);
    vd[0]=bf2f(vv.x&0xffff); vd[1]=bf2f(vv.x>>16); vd[2]=bf2f(vv.y&0xffff); vd[3]=bf2f(vv.y>>16);
    vd[4]=bf2f(vv.z&0xffff); vd[5]=bf2f(vv.z>>16); vd[6]=bf2f(vv.w&0xffff); vd[7]=bf2f(vv.w>>16);
  }
  float q[64];
  const bf16_t* qrow = base + (size_t)tid*2304 + h*64;
  #pragma unroll
  for (int d8=0; d8<8; d8++){
    uint4 qv = *(const uint4*)(qrow + d8*8);
    float* qd = &q[d8*8];
    qd[0]=bf2f(qv.x&0xffff)*0.125f; qd[1]=bf2f(qv.x>>16)*0.125f;
    qd[2]=bf2f(qv.y&0xffff)*0.125f; qd[3]=bf2f(qv.y>>16)*0.125f;
    qd[4]=bf2f(qv.z&0xffff)*0.125f; qd[5]=bf2f(qv.z>>16)*0.125f;
    qd[6]=bf2f(qv.w&0xffff)*0.125f; qd[7]=bf2f(qv.w>>16)*0.125f;
  }
  __syncthreads();

  float m = -1e30f, l = 0.f;
  float acc[64];
  #pragma unroll
  for (int d=0; d<64; d++) acc[d]=0.f;

  for (int k=0;k<256;k++){
    const float4* krow = (const float4*)&Ks[k][0];
    float s0=0.f,s1=0.f,s2=0.f,s3=0.f;
    #pragma unroll
    for (int d4=0; d4<16; d4++){
      float4 kv = krow[d4];
      s0 = fmaf(q[d4*4+0], kv.x, s0);
      s1 = fmaf(q[d4*4+1], kv.y, s1);
      s2 = fmaf(q[d4*4+2], kv.z, s2);
      s3 = fmaf(q[d4*4+3], kv.w, s3);
    }
    float s = (s0+s1)+(s2+s3);
    float mn = fmaxf(m, s);
    float corr = __expf(m - mn);
    float p = __expf(s - mn);
    l = l*corr + p;
    m = mn;
    const float4* vrow = (const float4*)&Vs[k][0];
    #pragma unroll
    for (int d4=0; d4<16; d4++){
      float4 vv = vrow[d4];
      acc[d4*4+0] = fmaf(acc[d4*4+0], corr, p*vv.x);
      acc[d4*4+1] = fmaf(acc[d4*4+1], corr, p*vv.y);
      acc[d4*4+2] = fmaf(acc[d4*4+2], corr, p*vv.z);
      acc[d4*4+3] = fmaf(acc[d4*4+3], corr, p*vv.w);
    }
  }
  float inv = 1.f/l;
  bf16_t* orow = o + (size_t)(b*NPP + tid)*D + h*64;
  #pragma unroll
  for (int d8=0; d8<8; d8++){
    uint4 sv;
    sv.x = (unsigned)f2bf(acc[d8*8+0]*inv) | ((unsigned)f2bf(acc[d8*8+1]*inv)<<16);
    sv.y = (unsigned)f2bf(acc[d8*8+2]*inv) | ((unsigned)f2bf(acc[d8*8+3]*inv)<<16);
    sv.z = (unsigned)f2bf(acc[d8*8+4]*inv) | ((unsigned)f2bf(acc[d8*8+5]*inv)<<16);
    sv.w = (unsigned)f2bf(acc[d8*8+6]*inv) | ((unsigned)f2bf(acc[d8*8+7]*inv)<<16);
    *(uint4*)(orow + d8*8) = sv;
  }
}

// ---------------- final linear + unpatchify ----------------
__global__ void k_final(const float* __restrict__ tokf, const float* __restrict__ w,
                        const float* __restrict__ bias, float* __restrict__ out){
  int idx = blockIdx.x*256 + threadIdx.x;   // NTOK*16
  int j = idx & 15, tk = idx >> 4;
  const float* a = tokf + (size_t)tk*D;
  float acc = bias[j];
  #pragma unroll 4
  for (int k=0;k<D;k++) acc = fmaf(a[k], w[k*16 + j], acc);
  int b = tk >> 8, n = tk & 255;
  int hi = n >> 4, wi = n & 15;
  int p1 = j >> 3, p2 = (j >> 2) & 1, c = j & 3;
  out[((size_t)(b*4 + c)*32 + hi*2 + p1)*32 + wi*2 + p2] = acc;
}

extern "C" void kernel_launch(void* const* d_in, const int* in_sizes, int n_in,
                              void* d_out, int out_size, void* d_ws, size_t ws_size,
                              hipStream_t stream){
  const float* x         = (const float*)d_in[0];
  const float* t         = (const float*)d_in[1];
  const float* conv_w    = (const float*)d_in[2];
  const float* conv_b    = (const float*)d_in[3];
  const float* tmlp_w1   = (const float*)d_in[4];
  const float* tmlp_b1   = (const float*)d_in[5];
  const float* tmlp_w2   = (const float*)d_in[6];
  const float* tmlp_b2   = (const float*)d_in[7];
  const float* cls_emb   = (const float*)d_in[8];
  const float* qkv_w     = (const float*)d_in[9];
  const float* qkv_b     = (const float*)d_in[10];
  const float* outp_w    = (const float*)d_in[11];
  const float* outp_b    = (const float*)d_in[12];
  const float* ada_w     = (const float*)d_in[13];
  const float* ada_b     = (const float*)d_in[14];
  const float* mlp_w1    = (const float*)d_in[15];
  const float* mlp_b1    = (const float*)d_in[16];
  const float* mlp_w2    = (const float*)d_in[17];
  const float* mlp_b2    = (const float*)d_in[18];
  const float* fin_ada_w = (const float*)d_in[19];
  const float* fin_ada_b = (const float*)d_in[20];
  const float* fin_lin_w = (const float*)d_in[21];
  const float* fin_lin_b = (const float*)d_in[22];
  const int*   label     = (const int*)d_in[23];
  float* out = (float*)d_out;

  // ---- workspace layout ----
  char* wp = (char*)d_ws;
  float*  tok     = (float*)wp;    wp += (size_t)NTOK*D*4;
  bf16_t* bigb    = (bf16_t*)wp;   wp += (size_t)NTOK*3072*2;
  bf16_t* hmodb   = (bf16_t*)wp;   wp += (size_t)NTOK*D*2;
  bf16_t* oattb   = (bf16_t*)wp;   wp += (size_t)NTOK*D*2;
  bf16_t* wqT     = (bf16_t*)wp;   wp += (size_t)2304*768*2;
  bf16_t* woT     = (bf16_t*)wp;   wp += (size_t)768*768*2;
  bf16_t* w1T     = (bf16_t*)wp;   wp += (size_t)3072*768*2;
  bf16_t* w2T     = (bf16_t*)wp;   wp += (size_t)768*3072*2;
  float*  c0      = (float*)wp;    wp += (size_t)NB*D*4;
  float*  chid    = (float*)wp;    wp += (size_t)NB*3072*4;
  float*  cvec    = (float*)wp;    wp += (size_t)NB*D*4;
  float*  scv     = (float*)wp;    wp += (size_t)NB*D*4;
  float*  ada_all = (float*)wp;    wp += (size_t)NB*ADATOT*4;   // 7.1MB
  float*  fada    = (float*)wp;    wp += (size_t)NB*1536*4;
  float*  hmodF   = (float*)bigb;  // final LN output aliases bigb

  k_patchify<<<NTOK*D/256, 256, 0, stream>>>(x, conv_w, conv_b, tok);
  k_timeembed<<<(NB*D)/256, 256, 0, stream>>>(t, c0);
  k_gemm_skinny<1><<<dim3(3072/64, NB), 256, 0, stream>>>(c0,   tmlp_w1, tmlp_b1, chid, 3072, 3072, 768,  nullptr, nullptr);
  k_gemm_skinny<2><<<dim3( 768/64, NB), 256, 0, stream>>>(chid, tmlp_w2, tmlp_b2, cvec,  768,  768, 3072, cls_emb, label);
  k_silu<<<(NB*D)/256, 256, 0, stream>>>(cvec, scv, NB*D);
  // all 12 layers' adaLN vectors in one dispatch
  k_gemm_skinny<0><<<dim3(ADATOT/64, NB), 256, 0, stream>>>(scv, ada_w, ada_b, ada_all, ADATOT, ADA6, 768, nullptr, nullptr);
  k_gemm_skinny<0><<<dim3(1536/64, NB), 256, 0, stream>>>(scv, fin_ada_w, fin_ada_b, fada, 1536, 1536, 768, nullptr, nullptr);

  for (int i=0;i<NLAY;i++){
    const float* qw  = qkv_w  + (size_t)i*768*2304;
    const float* qb  = qkv_b  + (size_t)i*2304;
    const float* ow  = outp_w + (size_t)i*768*768;
    const float* ob  = outp_b + (size_t)i*768;
    const float* m1w = mlp_w1 + (size_t)i*768*3072;
    const float* m1b = mlp_b1 + (size_t)i*3072;
    const float* m2w = mlp_w2 + (size_t)i*3072*768;
    const float* m2b = mlp_b2 + (size_t)i*768;
    int ao = i*ADA6;

    // per-layer weight convert+transpose: fp32 [K][N] -> bf16 [N][K]
    k_w2bf16t<<<dim3(2304/32,  768/32), 256, 0, stream>>>(qw,  wqT, 768, 2304);
    k_w2bf16t<<<dim3( 768/32,  768/32), 256, 0, stream>>>(ow,  woT, 768, 768);
    k_w2bf16t<<<dim3(3072/32,  768/32), 256, 0, stream>>>(m1w, w1T, 768, 3072);
    k_w2bf16t<<<dim3( 768/32, 3072/32), 256, 0, stream>>>(m2w, w2T, 3072, 768);

    k_lnmod<bf16_t><<<NTOK, 256, 0, stream>>>(tok, ada_all, hmodb, ADATOT, ao+0, ao+768);
    k_gemm_mfma<0><<<dim3(2304/128, NTOK/128), 256, 0, stream>>>(hmodb, wqT, qb, bigb, nullptr, 2304, 768, nullptr, 0, 0);
    k_attn<<<NB*NHEAD, 256, 0, stream>>>(bigb, oattb);
    k_gemm_mfma<2><<<dim3( 768/128, NTOK/128), 256, 0, stream>>>(oattb, woT, ob, nullptr, tok, 768, 768, ada_all, ADATOT, ao+1536);
    k_lnmod<bf16_t><<<NTOK, 256, 0, stream>>>(tok, ada_all, hmodb, ADATOT, ao+2304, ao+3072);
    k_gemm_mfma<1><<<dim3(3072/128, NTOK/128), 256, 0, stream>>>(hmodb, w1T, m1b, bigb, nullptr, 3072, 768, nullptr, 0, 0);
    k_gemm_mfma<2><<<dim3( 768/128, NTOK/128), 256, 0, stream>>>(bigb, w2T, m2b, nullptr, tok, 768, 3072, ada_all, ADATOT, ao+3840);
  }

  k_lnmod<float><<<NTOK, 256, 0, stream>>>(tok, fada, hmodF, 1536, 0, 768);
  k_final<<<NTOK*16/256, 256, 0, stream>>>(hmodF, fin_lin_w, fin_lin_b, out);
}